// Round 4
// baseline (330.898 us; speedup 1.0000x reference)
//
#include <hip/hip_runtime.h>
#include <math.h>

#define KK 64
#define DD 256
#define GX 128        // blocks per feature (1 block/CU total with x2 features)
#define TROWS 32      // rows per staged tile (32 KB)
#define MAXCHUNK 1024 // max rows per block (N<=GX*MAXCHUNK)
#define INV_TAU 2.0f
#define EPSL 1e-8f

typedef __attribute__((address_space(1))) const void gvoid;
typedef __attribute__((address_space(3))) void svoid;
typedef __attribute__((address_space(3))) float lfloat;

// hardware LDS f32 atomic add — bypasses LLVM's CAS-loop expansion of
// atomicrmw fadd (denormal-mode gate). Fire-and-forget on the DS pipe.
__device__ __forceinline__ void lds_fadd(float* p, float v) {
    unsigned a = (unsigned)(size_t)(lfloat*)p;   // addrspacecast -> 32-bit LDS offset
    asm volatile("ds_add_f32 %0, %1" :: "v"(a), "v"(v) : "memory");
}

// ws float layout:
// P : [2][GX][K*D]   per-block partial sums (16 MB)
// C : [2][GX][K]     per-block partial counts
// AR: [2][K*D]       normalized prototypes
// lossk: [K]

__global__ __launch_bounds__(256) void seg_partial_kernel(
    const float* __restrict__ fa, const float* __restrict__ fr,
    const int* __restrict__ la, const int* __restrict__ lr,
    float* __restrict__ P, float* __restrict__ C, int N)
{
    __shared__ float acc[KK * DD];            // 64 KB
    __shared__ float stage[2][TROWS * DD];    // 2 x 32 KB
    __shared__ int lbl[MAXCHUNK];
    __shared__ int cnt[KK];

    const int tid = threadIdx.x;
    const int g = blockIdx.x, f = blockIdx.y;
    const float* __restrict__ feat = f ? fr : fa;
    const int* __restrict__ label = f ? lr : la;

    float4* a4 = (float4*)acc;
    for (int i = tid; i < KK * DD / 4; i += 256) a4[i] = make_float4(0.f, 0.f, 0.f, 0.f);
    if (tid < KK) cnt[tid] = 0;

    const int chunk = (N + GX - 1) / GX;
    const int n0 = g * chunk;
    const int n1 = min(N, n0 + chunk);
    const int rows = n1 - n0;

    __syncthreads();
    for (int i = tid; i < rows; i += 256) lbl[i] = label[n0 + i];
    __syncthreads();
    for (int i = tid; i < rows; i += 256) atomicAdd(&cnt[lbl[i]], 1);  // int: hw ds_add_u32

    const int nt = (rows + TROWS - 1) / TROWS;
    const int w = tid >> 6, lane = tid & 63;
    const size_t limit = (size_t)N * DD - 4;  // last safe start element for a 16B load

    // stage tile t (32 rows x 256 f32, flat-contiguous in global) into stage[t&1]
    // per wave: 8 x global_load_lds dwordx4 (1 KB each), LDS dest wave-uniform base
    #define STAGE(t)                                                                     \
    do {                                                                                 \
        const size_t base_ = ((size_t)(n0 + (t) * TROWS)) * DD + (size_t)w * 2048 + lane * 4; \
        float* lb_ = &stage[(t) & 1][w * 2048];                                          \
        _Pragma("unroll")                                                                \
        for (int i_ = 0; i_ < 8; ++i_) {                                                 \
            size_t e_ = base_ + i_ * 256;                                                \
            if (e_ > limit) e_ = 0;  /* clamp OOB reads on tail tile */                  \
            __builtin_amdgcn_global_load_lds((gvoid*)(feat + e_), (svoid*)(lb_ + i_ * 256), 16, 0, 0); \
        }                                                                                \
    } while (0)

    if (nt > 0) STAGE(0);
    for (int t = 0; t < nt; ++t) {
        if (t + 1 < nt) {
            STAGE(t + 1);
            asm volatile("s_waitcnt vmcnt(8)" ::: "memory");  // tile t landed, t+1 in flight
        } else {
            asm volatile("s_waitcnt vmcnt(0)" ::: "memory");
        }
        __builtin_amdgcn_s_barrier();

        const int rn = min(TROWS, rows - t * TROWS);
        const float* sb = stage[t & 1];
        const int* lb = lbl + t * TROWS;
        int r = 0;
        for (; r + 8 <= rn; r += 8) {
            int l[8];
            float v[8];
            #pragma unroll
            for (int u = 0; u < 8; ++u) l[u] = lb[r + u];
            #pragma unroll
            for (int u = 0; u < 8; ++u) v[u] = sb[(r + u) * DD + tid];
            #pragma unroll
            for (int u = 0; u < 8; ++u) lds_fadd(&acc[l[u] * DD + tid], v[u]); // ds_add_f32
        }
        for (; r < rn; ++r)
            lds_fadd(&acc[lb[r] * DD + tid], sb[r * DD + tid]);

        asm volatile("s_waitcnt lgkmcnt(0)" ::: "memory");    // my reads+adds of buf done
        __builtin_amdgcn_s_barrier();                          // everyone's done
    }

    float4* dst = (float4*)(P + ((size_t)f * GX + g) * (KK * DD));
    for (int i = tid; i < KK * DD / 4; i += 256) dst[i] = a4[i];
    if (tid < KK) C[((size_t)f * GX + g) * KK + tid] = (float)cnt[tid];
    #undef STAGE
}

__global__ __launch_bounds__(256) void proto_norm_kernel(
    const float* __restrict__ P, const float* __restrict__ C,
    float* __restrict__ AR, int G)
{
    const int k = blockIdx.x, f = blockIdx.y, tid = threadIdx.x;
    const float* base = P + (size_t)f * G * (KK * DD) + (size_t)k * DD + tid;

    float s = 0.0f;
    int g = 0;
    for (; g + 8 <= G; g += 8) {
        float v[8];
        #pragma unroll
        for (int u = 0; u < 8; ++u) v[u] = base[(size_t)(g + u) * (KK * DD)];
        #pragma unroll
        for (int u = 0; u < 8; ++u) s += v[u];
    }
    for (; g < G; ++g) s += base[(size_t)g * (KK * DD)];

    float c = 0.0f;
    const float* cb = C + (size_t)f * G * KK + k;
    for (int g2 = 0; g2 < G; ++g2) c += cb[(size_t)g2 * KK];

    const float m = s / c;
    float sq = m * m;
    #pragma unroll
    for (int i = 1; i < 64; i <<= 1) sq += __shfl_xor(sq, i, 64);
    __shared__ float red[4];
    const int wid = tid >> 6, lane = tid & 63;
    if (lane == 0) red[wid] = sq;
    __syncthreads();
    const float nrm = red[0] + red[1] + red[2] + red[3];
    AR[(size_t)f * KK * DD + (size_t)k * DD + tid] = m / fmaxf(sqrtf(nrm), 1e-12f);
}

__global__ __launch_bounds__(256) void loss_kernel(const float* __restrict__ AR,
                                                   float* __restrict__ lossk)
{
    const float* A = AR;
    const float* R = AR + KK * DD;
    const int k = blockIdx.x, tid = threadIdx.x;

    const float a = A[k * DD + tid];
    const float r = R[k * DD + tid];
    const float lfp = a * r * INV_TAU;
    const float fp = expf(lfp);
    float ssa = 0.0f, ssr = 0.0f;
    #pragma unroll 8
    for (int j = 0; j < KK; ++j) {
        ssa += expf(a * A[j * DD + tid] * INV_TAU);
        ssr += expf(a * R[j * DD + tid] * INV_TAU);
    }
    const float Fn = (ssa - expf(a * a * INV_TAU)) + (ssr - fp) + 2.0f * (KK - 1) * fp;
    float l = logf(Fn + EPSL) - lfp;

    #pragma unroll
    for (int i = 1; i < 64; i <<= 1) l += __shfl_xor(l, i, 64);
    __shared__ float red[4];
    const int wid = tid >> 6, lane = tid & 63;
    if (lane == 0) red[wid] = l;
    __syncthreads();
    if (tid == 0) lossk[k] = (red[0] + red[1] + red[2] + red[3]) * (1.0f / DD);
}

__global__ void final_kernel(const float* __restrict__ lossk, float* __restrict__ out)
{
    float v = lossk[threadIdx.x];
    #pragma unroll
    for (int i = 1; i < 64; i <<= 1) v += __shfl_xor(v, i, 64);
    if (threadIdx.x == 0) out[0] = v;
}

extern "C" void kernel_launch(void* const* d_in, const int* in_sizes, int n_in,
                              void* d_out, int out_size, void* d_ws, size_t ws_size,
                              hipStream_t stream)
{
    const float* fa = (const float*)d_in[0];
    const float* fr = (const float*)d_in[1];
    const int* la = (const int*)d_in[2];
    const int* lr = (const int*)d_in[3];
    float* ws = (float*)d_ws;
    float* out = (float*)d_out;
    const int N = in_sizes[2];

    float* P = ws;                                  // [2][GX][K*D]
    float* C = P + 2L * GX * KK * DD;               // [2][GX][K]
    float* AR = C + 2L * GX * KK;                   // [2][K*D]
    float* lossk = AR + 2L * KK * DD;               // [K]

    seg_partial_kernel<<<dim3(GX, 2), 256, 0, stream>>>(fa, fr, la, lr, P, C, N);
    proto_norm_kernel<<<dim3(KK, 2), 256, 0, stream>>>(P, C, AR, GX);
    loss_kernel<<<KK, 256, 0, stream>>>(AR, lossk);
    final_kernel<<<1, 64, 0, stream>>>(lossk, out);
}

// Round 5
// 123.929 us; speedup vs baseline: 2.6701x; 2.6701x over previous
//
#include <hip/hip_runtime.h>
#include <math.h>

#define KK 64
#define DD 256
#define GX 256        // blocks per feature (2 blocks/CU with x2 features)
#define TROWS 32      // rows per staged tile (32 KB)
#define MAXCHUNK 512  // max rows per block (N <= GX*MAXCHUNK)
#define INV_TAU 2.0f
#define EPSL 1e-8f

typedef __attribute__((address_space(1))) const void gvoid;
typedef __attribute__((address_space(3))) void svoid;

// ws float layout:
// P : [2][GX][K*D]   per-block partial sums (33.5 MB)
// C : [2][GX][K]     per-block partial counts
// AR: [2][K*D]       normalized prototypes
// lossk: [K]

__global__ __launch_bounds__(256) void seg_partial_kernel(
    const float* __restrict__ fa, const float* __restrict__ fr,
    const int* __restrict__ la, const int* __restrict__ lr,
    float* __restrict__ P, float* __restrict__ C, int N)
{
    __shared__ float stage[2][TROWS * DD];    // 2 x 32 KB
    __shared__ int lbl[MAXCHUNK];
    __shared__ int cnt[KK];

    const int tid = threadIdx.x;
    const int g = blockIdx.x, f = blockIdx.y;
    const float* __restrict__ feat = f ? fr : fa;
    const int* __restrict__ label = f ? lr : la;

    if (tid < KK) cnt[tid] = 0;

    const int chunk = (N + GX - 1) / GX;
    const int n0 = g * chunk;
    int rows = min(N, n0 + chunk) - n0;
    if (rows < 0) rows = 0;

    __syncthreads();
    for (int i = tid; i < rows; i += 256) lbl[i] = label[n0 + i];
    __syncthreads();
    for (int i = tid; i < rows; i += 256) atomicAdd(&cnt[lbl[i]], 1);  // tiny, off hot path

    // register accumulator: thread owns column d == tid, all K rows.
    // statically indexed via fully-unrolled k loops -> stays in VGPRs.
    float accr[KK];
    #pragma unroll
    for (int k = 0; k < KK; ++k) accr[k] = 0.0f;

    const int nt = (rows + TROWS - 1) / TROWS;
    const int w = tid >> 6, lane = tid & 63;
    const size_t limit = (size_t)N * DD - 4;  // last safe start element for a 16B load

    // stage tile t (32 rows x 256 f32, flat-contiguous in global) into stage[t&1]
    // per wave: 8 x global_load_lds dwordx4 (1 KB each), LDS dest wave-uniform base
    #define STAGE(t)                                                                     \
    do {                                                                                 \
        const size_t base_ = ((size_t)(n0 + (t) * TROWS)) * DD + (size_t)w * 2048 + lane * 4; \
        float* lb_ = &stage[(t) & 1][w * 2048];                                          \
        _Pragma("unroll")                                                                \
        for (int i_ = 0; i_ < 8; ++i_) {                                                 \
            size_t e_ = base_ + i_ * 256;                                                \
            if (e_ > limit) e_ = 0;  /* clamp OOB reads on tail tile */                  \
            __builtin_amdgcn_global_load_lds((gvoid*)(feat + e_), (svoid*)(lb_ + i_ * 256), 16, 0, 0); \
        }                                                                                \
    } while (0)

    if (nt > 0) STAGE(0);
    for (int t = 0; t < nt; ++t) {
        if (t + 1 < nt) {
            STAGE(t + 1);
            asm volatile("s_waitcnt vmcnt(8)" ::: "memory");  // tile t landed, t+1 in flight
        } else {
            asm volatile("s_waitcnt vmcnt(0)" ::: "memory");
        }
        __builtin_amdgcn_s_barrier();

        const int rn = min(TROWS, rows - t * TROWS);
        const float* sb = stage[t & 1];
        const int* lb = lbl + t * TROWS;
        const int myl = (lane < rn) ? lb[lane] : -1;   // lanes >= rn never match

        #pragma unroll
        for (int k = 0; k < KK; ++k) {
            unsigned long long m = __ballot(myl == k);  // wave-uniform, identical in all 4 waves
            while (m) {
                const int r = (int)__builtin_ctzll(m);  // uniform row index
                m &= m - 1;
                accr[k] += sb[r * DD + tid];            // ds_read_b32, conflict-free
            }
        }

        asm volatile("s_waitcnt lgkmcnt(0)" ::: "memory");  // my reads of buf done
        __builtin_amdgcn_s_barrier();                        // everyone's reads done
    }

    // plain coalesced stores of this block's partial (no atomics)
    float* dst = P + ((size_t)f * GX + g) * (KK * DD) + tid;
    #pragma unroll
    for (int k = 0; k < KK; ++k) dst[(size_t)k * DD] = accr[k];
    __syncthreads();
    if (tid < KK) C[((size_t)f * GX + g) * KK + tid] = (float)cnt[tid];
    #undef STAGE
}

__global__ __launch_bounds__(256) void proto_norm_kernel(
    const float* __restrict__ P, const float* __restrict__ C,
    float* __restrict__ AR, int G)
{
    const int k = blockIdx.x, f = blockIdx.y, tid = threadIdx.x;
    const float* base = P + (size_t)f * G * (KK * DD) + (size_t)k * DD + tid;

    float s = 0.0f;
    int g = 0;
    for (; g + 8 <= G; g += 8) {
        float v[8];
        #pragma unroll
        for (int u = 0; u < 8; ++u) v[u] = base[(size_t)(g + u) * (KK * DD)];
        #pragma unroll
        for (int u = 0; u < 8; ++u) s += v[u];
    }
    for (; g < G; ++g) s += base[(size_t)g * (KK * DD)];

    float c = 0.0f;
    const float* cb = C + (size_t)f * G * KK + k;
    for (int g2 = 0; g2 < G; ++g2) c += cb[(size_t)g2 * KK];

    const float m = s / c;
    float sq = m * m;
    #pragma unroll
    for (int i = 1; i < 64; i <<= 1) sq += __shfl_xor(sq, i, 64);
    __shared__ float red[4];
    const int wid = tid >> 6, lane = tid & 63;
    if (lane == 0) red[wid] = sq;
    __syncthreads();
    const float nrm = red[0] + red[1] + red[2] + red[3];
    AR[(size_t)f * KK * DD + (size_t)k * DD + tid] = m / fmaxf(sqrtf(nrm), 1e-12f);
}

__global__ __launch_bounds__(256) void loss_kernel(const float* __restrict__ AR,
                                                   float* __restrict__ lossk)
{
    const float* A = AR;
    const float* R = AR + KK * DD;
    const int k = blockIdx.x, tid = threadIdx.x;

    const float a = A[k * DD + tid];
    const float r = R[k * DD + tid];
    const float lfp = a * r * INV_TAU;
    const float fp = expf(lfp);
    float ssa = 0.0f, ssr = 0.0f;
    #pragma unroll 8
    for (int j = 0; j < KK; ++j) {
        ssa += expf(a * A[j * DD + tid] * INV_TAU);
        ssr += expf(a * R[j * DD + tid] * INV_TAU);
    }
    const float Fn = (ssa - expf(a * a * INV_TAU)) + (ssr - fp) + 2.0f * (KK - 1) * fp;
    float l = logf(Fn + EPSL) - lfp;

    #pragma unroll
    for (int i = 1; i < 64; i <<= 1) l += __shfl_xor(l, i, 64);
    __shared__ float red[4];
    const int wid = tid >> 6, lane = tid & 63;
    if (lane == 0) red[wid] = l;
    __syncthreads();
    if (tid == 0) lossk[k] = (red[0] + red[1] + red[2] + red[3]) * (1.0f / DD);
}

__global__ void final_kernel(const float* __restrict__ lossk, float* __restrict__ out)
{
    float v = lossk[threadIdx.x];
    #pragma unroll
    for (int i = 1; i < 64; i <<= 1) v += __shfl_xor(v, i, 64);
    if (threadIdx.x == 0) out[0] = v;
}

extern "C" void kernel_launch(void* const* d_in, const int* in_sizes, int n_in,
                              void* d_out, int out_size, void* d_ws, size_t ws_size,
                              hipStream_t stream)
{
    const float* fa = (const float*)d_in[0];
    const float* fr = (const float*)d_in[1];
    const int* la = (const int*)d_in[2];
    const int* lr = (const int*)d_in[3];
    float* ws = (float*)d_ws;
    float* out = (float*)d_out;
    const int N = in_sizes[2];

    float* P = ws;                                  // [2][GX][K*D]
    float* C = P + 2L * GX * KK * DD;               // [2][GX][K]
    float* AR = C + 2L * GX * KK;                   // [2][K*D]
    float* lossk = AR + 2L * KK * DD;               // [K]

    seg_partial_kernel<<<dim3(GX, 2), 256, 0, stream>>>(fa, fr, la, lr, P, C, N);
    proto_norm_kernel<<<dim3(KK, 2), 256, 0, stream>>>(P, C, AR, GX);
    loss_kernel<<<KK, 256, 0, stream>>>(AR, lossk);
    final_kernel<<<1, 64, 0, stream>>>(lossk, out);
}

// Round 6
// 115.667 us; speedup vs baseline: 2.8608x; 1.0714x over previous
//
#include <hip/hip_runtime.h>
#include <math.h>

#define KK 64
#define DD 256
#define GX 256        // blocks per feature; grid = 512 blocks = 2/CU exactly
#define TROWS 32      // rows per staged tile (32 KB)
#define MAXCHUNK 512  // max rows per block (N <= GX*MAXCHUNK)
#define INV_TAU 2.0f
#define EPSL 1e-8f

typedef __attribute__((address_space(1))) const void gvoid;
typedef __attribute__((address_space(3))) void svoid;

// ws float layout:
// P : [2][GX][K*D]   per-block partial sums (33.5 MB)
// C : [2][GX][K]     per-block partial counts
// AR: [2][K*D]       normalized prototypes
// lossk: [K]

__global__ __launch_bounds__(512, 4) void seg_partial_kernel(
    const float* __restrict__ fa, const float* __restrict__ fr,
    const int* __restrict__ la, const int* __restrict__ lr,
    float* __restrict__ P, float* __restrict__ C, int N)
{
    __shared__ __attribute__((aligned(16))) float stage[2][TROWS * DD]; // 2 x 32 KB
    __shared__ int lbl[MAXCHUNK];
    __shared__ int cnt[KK];

    const int tid = threadIdx.x;
    const int g = blockIdx.x, f = blockIdx.y;
    const float* __restrict__ feat = f ? fr : fa;
    const int* __restrict__ label = f ? lr : la;

    if (tid < KK) cnt[tid] = 0;

    const int chunk = (N + GX - 1) / GX;
    const int n0 = g * chunk;
    int rows = min(N, n0 + chunk) - n0;
    if (rows < 0) rows = 0;

    __syncthreads();
    for (int i = tid; i < rows; i += 512) lbl[i] = label[n0 + i];
    __syncthreads();
    for (int i = tid; i < rows; i += 512) atomicAdd(&cnt[lbl[i]], 1); // tiny, off hot path

    // wave w owns classes [8w, 8w+8); lane l owns columns 4l..4l+3.
    // accumulator statically indexed -> stays in VGPRs (32 regs).
    float accr[8][4];
    #pragma unroll
    for (int i = 0; i < 8; ++i)
        #pragma unroll
        for (int j = 0; j < 4; ++j) accr[i][j] = 0.0f;

    const int nt = (rows + TROWS - 1) / TROWS;
    const int w = tid >> 6, lane = tid & 63;
    const int k0 = 8 * w;
    const size_t limit = (size_t)N * DD - 4;  // last safe start element for a 16B load

    // stage tile t (32 rows x 256 f32, flat-contiguous in global) into stage[t&1]
    // 8 waves x 4 global_load_lds dwordx4 (1 KB each); LDS dest wave-uniform base
    #define STAGE(t)                                                                     \
    do {                                                                                 \
        const size_t base_ = ((size_t)(n0 + (t) * TROWS)) * DD + (size_t)w * 1024 + lane * 4; \
        float* lb_ = &stage[(t) & 1][w * 1024];                                          \
        _Pragma("unroll")                                                                \
        for (int i_ = 0; i_ < 4; ++i_) {                                                 \
            size_t e_ = base_ + i_ * 256;                                                \
            if (e_ > limit) e_ = 0;  /* clamp OOB reads on tail tile */                  \
            __builtin_amdgcn_global_load_lds((gvoid*)(feat + e_), (svoid*)(lb_ + i_ * 256), 16, 0, 0); \
        }                                                                                \
    } while (0)

    if (nt > 0) STAGE(0);
    for (int t = 0; t < nt; ++t) {
        if (t + 1 < nt) {
            STAGE(t + 1);
            asm volatile("s_waitcnt vmcnt(4)" ::: "memory");  // tile t landed, t+1 in flight
        } else {
            asm volatile("s_waitcnt vmcnt(0)" ::: "memory");
        }
        __builtin_amdgcn_s_barrier();

        const int rn = min(TROWS, rows - t * TROWS);
        const float* sb = stage[t & 1];
        const int* lb = lbl + t * TROWS;
        // lane r (<32) carries row r's label; lanes >= rn never match
        const int myl = (lane < rn) ? lb[lane] : -1;

        #pragma unroll
        for (int i = 0; i < 8; ++i) {
            unsigned long long m = __ballot(myl == (k0 + i));  // wave-uniform mask
            while (m) {
                const int r = (int)__builtin_ctzll(m);          // uniform row index
                m &= m - 1;
                const float4 v = *(const float4*)(sb + r * DD + 4 * lane); // ds_read_b128
                accr[i][0] += v.x; accr[i][1] += v.y;
                accr[i][2] += v.z; accr[i][3] += v.w;
            }
        }

        asm volatile("s_waitcnt lgkmcnt(0)" ::: "memory");  // my reads of buf done
        __builtin_amdgcn_s_barrier();                        // everyone's reads done
    }

    // plain coalesced float4 stores of this block's partial (no atomics)
    float* dstb = P + ((size_t)f * GX + g) * (KK * DD);
    #pragma unroll
    for (int i = 0; i < 8; ++i) {
        float4 v = make_float4(accr[i][0], accr[i][1], accr[i][2], accr[i][3]);
        *(float4*)(dstb + (size_t)(k0 + i) * DD + 4 * lane) = v;
    }
    __syncthreads();
    if (tid < KK) C[((size_t)f * GX + g) * KK + tid] = (float)cnt[tid];
    #undef STAGE
}

__global__ __launch_bounds__(256) void proto_norm_kernel(
    const float* __restrict__ P, const float* __restrict__ C,
    float* __restrict__ AR, int G)
{
    const int k = blockIdx.x, f = blockIdx.y, tid = threadIdx.x;
    const float* base = P + (size_t)f * G * (KK * DD) + (size_t)k * DD + tid;

    float s = 0.0f;
    int g = 0;
    for (; g + 8 <= G; g += 8) {
        float v[8];
        #pragma unroll
        for (int u = 0; u < 8; ++u) v[u] = base[(size_t)(g + u) * (KK * DD)];
        #pragma unroll
        for (int u = 0; u < 8; ++u) s += v[u];
    }
    for (; g < G; ++g) s += base[(size_t)g * (KK * DD)];

    float c = 0.0f;
    const float* cb = C + (size_t)f * G * KK + k;
    for (int g2 = 0; g2 < G; ++g2) c += cb[(size_t)g2 * KK];

    const float m = s / c;
    float sq = m * m;
    #pragma unroll
    for (int i = 1; i < 64; i <<= 1) sq += __shfl_xor(sq, i, 64);
    __shared__ float red[4];
    const int wid = tid >> 6, lane = tid & 63;
    if (lane == 0) red[wid] = sq;
    __syncthreads();
    const float nrm = red[0] + red[1] + red[2] + red[3];
    AR[(size_t)f * KK * DD + (size_t)k * DD + tid] = m / fmaxf(sqrtf(nrm), 1e-12f);
}

__global__ __launch_bounds__(256) void loss_kernel(const float* __restrict__ AR,
                                                   float* __restrict__ lossk)
{
    const float* A = AR;
    const float* R = AR + KK * DD;
    const int k = blockIdx.x, tid = threadIdx.x;

    const float a = A[k * DD + tid];
    const float r = R[k * DD + tid];
    const float lfp = a * r * INV_TAU;
    const float fp = expf(lfp);
    float ssa = 0.0f, ssr = 0.0f;
    #pragma unroll 8
    for (int j = 0; j < KK; ++j) {
        ssa += expf(a * A[j * DD + tid] * INV_TAU);
        ssr += expf(a * R[j * DD + tid] * INV_TAU);
    }
    const float Fn = (ssa - expf(a * a * INV_TAU)) + (ssr - fp) + 2.0f * (KK - 1) * fp;
    float l = logf(Fn + EPSL) - lfp;

    #pragma unroll
    for (int i = 1; i < 64; i <<= 1) l += __shfl_xor(l, i, 64);
    __shared__ float red[4];
    const int wid = tid >> 6, lane = tid & 63;
    if (lane == 0) red[wid] = l;
    __syncthreads();
    if (tid == 0) lossk[k] = (red[0] + red[1] + red[2] + red[3]) * (1.0f / DD);
}

__global__ void final_kernel(const float* __restrict__ lossk, float* __restrict__ out)
{
    float v = lossk[threadIdx.x];
    #pragma unroll
    for (int i = 1; i < 64; i <<= 1) v += __shfl_xor(v, i, 64);
    if (threadIdx.x == 0) out[0] = v;
}

extern "C" void kernel_launch(void* const* d_in, const int* in_sizes, int n_in,
                              void* d_out, int out_size, void* d_ws, size_t ws_size,
                              hipStream_t stream)
{
    const float* fa = (const float*)d_in[0];
    const float* fr = (const float*)d_in[1];
    const int* la = (const int*)d_in[2];
    const int* lr = (const int*)d_in[3];
    float* ws = (float*)d_ws;
    float* out = (float*)d_out;
    const int N = in_sizes[2];

    float* P = ws;                                  // [2][GX][K*D]
    float* C = P + 2L * GX * KK * DD;               // [2][GX][K]
    float* AR = C + 2L * GX * KK;                   // [2][K*D]
    float* lossk = AR + 2L * KK * DD;               // [K]

    seg_partial_kernel<<<dim3(GX, 2), 512, 0, stream>>>(fa, fr, la, lr, P, C, N);
    proto_norm_kernel<<<dim3(KK, 2), 256, 0, stream>>>(P, C, AR, GX);
    loss_kernel<<<KK, 256, 0, stream>>>(AR, lossk);
    final_kernel<<<1, 64, 0, stream>>>(lossk, out);
}